// Round 5
// baseline (217.142 us; speedup 1.0000x reference)
//
#include <hip/hip_runtime.h>
#include <math.h>

#define NQ 22
#define DIM (1u << NQ)

typedef float v2f __attribute__((ext_vector_type(2)));

// Layouts:
//   blocked S(j) = mid<<13 | h<<3 | low   (low = j&7, mid = (j>>3)&511, h = j>>12)
//   buf1: passB stores amp x at T(x) (invGray/suffix-parity), so passA reads
//   contiguously: buf1[j] = S[G(j)], G(j) = j ^ (j>>1) = T^-1. This folds the
//   inter-layer CNOT chain into the store address (T is GF(2)-linear, so the
//   address is a per-thread base XOR a compile-time per-k constant).

__device__ __forceinline__ unsigned igray(unsigned x) {
  x ^= x >> 1; x ^= x >> 2; x ^= x >> 4; x ^= x >> 8; x ^= x >> 16;
  return x;
}

// ---------------- fused gate matrices: U = RZ * RY * RX, fp64 -> fp32 ----------------
__global__ void k_gates(const float* __restrict__ params, float* __restrict__ U) {
  int t = blockIdx.x * blockDim.x + threadIdx.x;
  if (t >= 88) return;               // t = l*22 + q
  const float* p = params + t * 3;
  double hx = 0.5 * (double)p[0], hy = 0.5 * (double)p[1], hz = 0.5 * (double)p[2];
  double cx = cos(hx), sx = sin(hx);
  double cy = cos(hy), sy = sin(hy);
  double cz = cos(hz), sz = sin(hz);
  double m00r = cy * cx, m00i = sy * sx;
  double m01r = -sy * cx, m01i = -cy * sx;
  double m10r = sy * cx, m10i = -cy * sx;
  double m11r = cy * cx, m11i = -sy * sx;
  float* o = U + t * 8;
  o[0] = (float)(cz * m00r + sz * m00i); o[1] = (float)(cz * m00i - sz * m00r);
  o[2] = (float)(cz * m01r + sz * m01i); o[3] = (float)(cz * m01i - sz * m01r);
  o[4] = (float)(cz * m10r - sz * m10i); o[5] = (float)(cz * m10i + sz * m10r);
  o[6] = (float)(cz * m11r - sz * m11i); o[7] = (float)(cz * m11i + sz * m11r);
}

// ---------------- packed gate application (N packs of 2 amps) ----------------
template <int NP>
__device__ __forceinline__ void apply_bit0(v2f RE[NP], v2f IM[NP], const float* __restrict__ u) {
  float u0 = u[0], u1 = u[1], u2 = u[2], u3 = u[3], u4 = u[4], u5 = u[5], u6 = u[6], u7 = u[7];
#pragma unroll
  for (int k = 0; k < NP; ++k) {
    float a0r = RE[k].x, a0i = IM[k].x, a1r = RE[k].y, a1i = IM[k].y;
    float n0r = u0 * a0r - u1 * a0i + u2 * a1r - u3 * a1i;
    float n0i = u0 * a0i + u1 * a0r + u2 * a1i + u3 * a1r;
    float n1r = u4 * a0r - u5 * a0i + u6 * a1r - u7 * a1i;
    float n1i = u4 * a0i + u5 * a0r + u6 * a1i + u7 * a1r;
    RE[k].x = n0r; IM[k].x = n0i; RE[k].y = n1r; IM[k].y = n1i;
  }
}

template <int NP, int PB>   // pair k-slots differing in bit PB
__device__ __forceinline__ void apply_bitP(v2f RE[NP], v2f IM[NP], const float* __restrict__ u) {
  float u0 = u[0], u1 = u[1], u2 = u[2], u3 = u[3], u4 = u[4], u5 = u[5], u6 = u[6], u7 = u[7];
#pragma unroll
  for (int m = 0; m < NP / 2; ++m) {
    int k0 = ((m >> PB) << (PB + 1)) | (m & ((1 << PB) - 1));
    int k1 = k0 | (1 << PB);
    v2f a0r = RE[k0], a0i = IM[k0], a1r = RE[k1], a1i = IM[k1];
    v2f n0r = u0 * a0r - u1 * a0i + u2 * a1r - u3 * a1i;
    v2f n0i = u0 * a0i + u1 * a0r + u2 * a1i + u3 * a1r;
    v2f n1r = u4 * a0r - u5 * a0i + u6 * a1r - u7 * a1i;
    v2f n1i = u4 * a0i + u5 * a0r + u6 * a1i + u7 * a1r;
    RE[k0] = n0r; IM[k0] = n0i; RE[k1] = n1r; IM[k1] = n1i;
  }
}

__device__ __forceinline__ void apply4p(v2f RE[8], v2f IM[8], const float* __restrict__ U,
                                        int l, int wtop) {
  const float* base = U + ((l * 22 + wtop) << 3);
  apply_bit0<8>(RE, IM, base);
  apply_bitP<8, 0>(RE, IM, base - 8);
  apply_bitP<8, 1>(RE, IM, base - 16);
  apply_bitP<8, 2>(RE, IM, base - 24);
}

// float2 (b64) LDS exchange for 16-amp state; used by passA.
template <typename WI, typename RI>
__device__ __forceinline__ void xchgP(float2* lds2, v2f RE[8], v2f IM[8], WI wi, RI ri) {
  __syncthreads();
#pragma unroll
  for (int d = 0; d < 16; ++d) {
    float2 a;
    if (d & 1) a = make_float2(RE[d >> 1].y, IM[d >> 1].y);
    else       a = make_float2(RE[d >> 1].x, IM[d >> 1].x);
    lds2[wi(d)] = a;
  }
  __syncthreads();
#pragma unroll
  for (int d = 0; d < 16; ++d) {
    float2 a = lds2[ri(d)];
    if (d & 1) { RE[d >> 1].y = a.x; IM[d >> 1].y = a.y; }
    else       { RE[d >> 1].x = a.x; IM[d >> 1].x = a.y; }
  }
}

// ---------------- pass A: gates on amp bits 0..11 (wires 21..10) ----------------
__global__ __launch_bounds__(256, 4) void k_passA(const float* __restrict__ srcRe,
                                                  const float* __restrict__ srcIm,
                                                  const float2* __restrict__ src2,
                                                  float2* __restrict__ dst,
                                                  const float* __restrict__ U,
                                                  int layer, int first) {
  __shared__ float2 lds2[4096];   // 32 KB; physical idx = j ^ (j>>4)
  const int t = threadIdx.x;
  const unsigned bid = blockIdx.x;
  const unsigned H = (bid & 7u) * (gridDim.x >> 3) + (bid >> 3);  // same-XCD chunks
  v2f RE[8], IM[8];
  if (first) {
    const unsigned jbase = (H << 12) | ((unsigned)t << 4);
    const float4* r4 = (const float4*)(srcRe + jbase);
    const float4* i4 = (const float4*)(srcIm + jbase);
#pragma unroll
    for (int k = 0; k < 4; ++k) {
      float4 r = r4[k], m = i4[k];
      RE[2 * k].x     = r.x; RE[2 * k].y     = r.y;
      IM[2 * k].x     = m.x; IM[2 * k].y     = m.y;
      RE[2 * k + 1].x = r.z; RE[2 * k + 1].y = r.w;
      IM[2 * k + 1].x = m.z; IM[2 * k + 1].y = m.w;
    }
  } else {
    const float4* s4 = (const float4*)(src2 + (((size_t)H << 12) | ((size_t)t << 4)));
#pragma unroll
    for (int k = 0; k < 8; ++k) {
      float4 a = s4[k];              // amps 2k (x,y), 2k+1 (z,w), re/im interleaved
      RE[k].x = a.x; IM[k].x = a.y;
      RE[k].y = a.z; IM[k].y = a.w;
    }
  }
  auto wA = [&](int d) { unsigned j = ((unsigned)t << 4) | (unsigned)d; return (int)(j ^ (j >> 4)); };
  auto rB = [&](int d) { unsigned j = (((unsigned)t >> 4) << 8) | ((unsigned)d << 4) | ((unsigned)t & 15); return (int)(j ^ (j >> 4)); };
  auto rC = [&](int d) { unsigned j = ((unsigned)d << 8) | (unsigned)t; return (int)(j ^ (j >> 4)); };

  apply4p(RE, IM, U, layer, 21);      // amp bits 0..3  -> wires 21..18
  xchgP(lds2, RE, IM, wA, rB);
  apply4p(RE, IM, U, layer, 17);      // bits 4..7 -> wires 17..14
  xchgP(lds2, RE, IM, rB, rC);
  apply4p(RE, IM, U, layer, 13);      // bits 8..11 -> wires 13..10
  // store from rC arrangement: slot d = amp m = d<<8|t; blocked addr
  float2* dp = dst + (((size_t)H << 3) | (unsigned)(t & 7));
#pragma unroll
  for (int d = 0; d < 16; ++d) {
    float2 a;
    if (d & 1) a = make_float2(RE[d >> 1].y, IM[d >> 1].y);
    else       a = make_float2(RE[d >> 1].x, IM[d >> 1].x);
    dp[(((size_t)d << 5) | (unsigned)(t >> 3)) << 13] = a;
  }
}

// ---------------- pass B v5: gates on amp bits 12..21 (wires 9..0) ----------------
// 16 amps/thread -> 16 waves/CU (grid 1024 = (mid, a2), 4 blocks/CU, 32 KB LDS).
// Block = 4096 amps: fixed (mid = amp 3..11, a2 = amp 2). Thread: c1 = t&1 (amp 1),
// u7 = t>>1 (7 of the 10 h bits). Regs: b (amp 0, v2f lane) + k (3 bits).
// 4 gate phases over h (amp 12..21 = wires 9..0), 3 float4 exchanges:
//   P0: h = k<<7|u7               k = h[7:9] -> wires 2,1,0
//   P1: h = u7<<3|k               k = h[0:2] -> wires 9,8,7
//   P2: h = (u7&7)|k<<3|(u7>>3)<<6    k = h[3:5] -> wires 6,5,4
//   P3: h = (u7&63)|k<<6|(u7>>6)<<9   k0 = h_6 -> wire 3
// LDS swizzle phi(o) = o ^ ((o>>4)&7)<<1: bank-floor on all 6 access maps.

__device__ __forceinline__ int phi(unsigned o) {
  return (int)(o ^ (((o >> 4) & 7u) << 1));
}

template <typename WI, typename RI>
__device__ __forceinline__ void xch4(float4* L, v2f RE[8], v2f IM[8], WI wi, RI ri) {
#pragma unroll
  for (int k = 0; k < 8; ++k)
    L[wi(k)] = make_float4(RE[k].x, IM[k].x, RE[k].y, IM[k].y);
  __syncthreads();
#pragma unroll
  for (int k = 0; k < 8; ++k) {
    float4 a = L[ri(k)];
    RE[k].x = a.x; IM[k].x = a.y; RE[k].y = a.z; IM[k].y = a.w;
  }
  __syncthreads();   // WAR for next buffer use
}

__device__ __forceinline__ void passB_core5(const float2* __restrict__ src,
                                            const float* __restrict__ B,
                                            float4* lds4, v2f RE[8], v2f IM[8],
                                            unsigned c1, unsigned u7,
                                            unsigned mid, unsigned a2) {
  // load: float4 idx = mid<<12 | k<<9 | u7<<2 | a2<<1 | c1
  const float4* sp4 = (const float4*)src + (((size_t)mid << 12) | (u7 << 2) | (a2 << 1) | c1);
#pragma unroll
  for (int k = 0; k < 8; ++k) {
    float4 a = sp4[(unsigned)k << 9];
    RE[k].x = a.x; IM[k].x = a.y; RE[k].y = a.z; IM[k].y = a.w;
  }
  // P0: wires 2,1,0 (h bits 7,8,9)
  apply_bitP<8, 0>(RE, IM, B + 2 * 8);
  apply_bitP<8, 1>(RE, IM, B + 1 * 8);
  apply_bitP<8, 2>(RE, IM, B + 0 * 8);
  auto w1 = [&](int k) { return phi(((((unsigned)k << 7) | u7) << 1) | c1); };
  auto r1 = [&](int k) { return phi((((u7 << 3) | (unsigned)k) << 1) | c1); };
  xch4(lds4, RE, IM, w1, r1);
  // P1: wires 9,8,7 (h bits 0,1,2)
  apply_bitP<8, 0>(RE, IM, B + 9 * 8);
  apply_bitP<8, 1>(RE, IM, B + 8 * 8);
  apply_bitP<8, 2>(RE, IM, B + 7 * 8);
  auto r2 = [&](int k) { return phi((((u7 & 7u) | ((unsigned)k << 3) | ((u7 >> 3) << 6)) << 1) | c1); };
  xch4(lds4, RE, IM, r1, r2);
  // P2: wires 6,5,4 (h bits 3,4,5)
  apply_bitP<8, 0>(RE, IM, B + 6 * 8);
  apply_bitP<8, 1>(RE, IM, B + 5 * 8);
  apply_bitP<8, 2>(RE, IM, B + 4 * 8);
  auto r3 = [&](int k) { return phi((((u7 & 63u) | ((unsigned)k << 6) | ((u7 >> 6) << 9)) << 1) | c1); };
  xch4(lds4, RE, IM, r2, r3);
  // P3: wire 3 (h bit 6 = k bit 0)
  apply_bitP<8, 0>(RE, IM, B + 3 * 8);
}

__global__ __launch_bounds__(256, 4) void k_passB(const float2* __restrict__ src,
                                                  float2* __restrict__ dst,
                                                  const float* __restrict__ U,
                                                  int layer) {
  __shared__ float4 lds4[2048];   // 32 KB
  const int t = threadIdx.x;
  const unsigned c1 = (unsigned)(t & 1), u7 = (unsigned)(t >> 1);
  const unsigned bid = blockIdx.x;
  const unsigned H = (bid & 7u) * (gridDim.x >> 3) + (bid >> 3);
  const unsigned mid = H >> 1, a2 = H & 1u;
  v2f RE[8], IM[8];
  passB_core5(src, U + layer * 22 * 8, lds4, RE, IM, c1, u7, mid, a2);
  // T-store: x = h<<12 | mid<<3 | a2<<2 | c1<<1 | b; h = (u7&63)|k<<6|(u7>>6)<<9
  const unsigned Tb = igray(((u7 & 63u) << 12) | ((u7 >> 6) << 21) |
                            (mid << 3) | (a2 << 2) | (c1 << 1));
  float4* dp4 = (float4*)dst;
#pragma unroll
  for (int k = 0; k < 8; ++k) {
    unsigned a2x = Tb ^ igray((unsigned)k << 18);   // folds at compile time
    float4 v = (a2x & 1u) ? make_float4(RE[k].y, IM[k].y, RE[k].x, IM[k].x)
                          : make_float4(RE[k].x, IM[k].x, RE[k].y, IM[k].y);
    dp4[a2x >> 1] = v;
  }
}

// ---------------- last-layer pass B fused with expvals (final-CNOT sign trick) ----------------
// amp bits: 0=b, 1=c1, 2=a2, 3..11=mid, 12..17=u7&63, 18..20=k, 21=u7>>6.
// wire q sign = parity(amp bits >= 21-q). Register folds over k and b:
//   W20 = (-1)^{k2}, W19 = ^{k2k1}, Wk = ^{all k}, Wkb = ^{all k + b}.
__global__ __launch_bounds__(256, 4) void k_passB_ev(const float2* __restrict__ src,
                                                     const float* __restrict__ U,
                                                     float* __restrict__ partials,
                                                     int layer) {
  __shared__ float4 lds4[2048];
  const int t = threadIdx.x;
  const unsigned c1 = (unsigned)(t & 1), u7 = (unsigned)(t >> 1);
  const unsigned bid = blockIdx.x;
  const unsigned H = (bid & 7u) * (gridDim.x >> 3) + (bid >> 3);
  const unsigned mid = H >> 1, a2 = H & 1u;
  v2f RE[8], IM[8];
  passB_core5(src, U + layer * 22 * 8, lds4, RE, IM, c1, u7, mid, a2);

  // ---- expval epilogue ----
  v2f PS[8];
#pragma unroll
  for (int k = 0; k < 8; ++k) PS[k] = RE[k] * RE[k] + IM[k] * IM[k];
  float Tot = 0.f, W20 = 0.f;
  v2f Ba[4];
#pragma unroll
  for (int j = 0; j < 4; ++j) {
    v2f S = PS[j] + PS[j + 4];
    Tot += S.x + S.y;
    Ba[j] = PS[j] - PS[j + 4];          // (-1)^{amp20}
    W20 += Ba[j].x + Ba[j].y;
  }
  v2f Bb0 = Ba[0] - Ba[2], Bb1 = Ba[1] - Ba[3];   // ^{amp19}
  float W19 = Bb0.x + Bb0.y + Bb1.x + Bb1.y;
  v2f Bc = Bb0 - Bb1;                   // ^{amp18}
  float Wk = Bc.x + Bc.y;
  float Wkb = Bc.x - Bc.y;              // + (-1)^{b}

  const unsigned s21 = (u7 >> 6) & 1u;
  const unsigned pu6 = (unsigned)__popc(u7 & 63u) & 1u;
  unsigned low = (mid << 3) | (a2 << 2) | (c1 << 1);
  unsigned y = low; y ^= y >> 1; y ^= y >> 2; y ^= y >> 4; y ^= y >> 8;  // suffix-XOR
  float acc[22];
  {
    float sg = s21 ? -1.f : 1.f;
    acc[0] = sg * Tot; acc[1] = sg * W20; acc[2] = sg * W19; acc[3] = sg * Wk;
  }
#pragma unroll
  for (int q = 4; q <= 8; ++q)
    acc[q] = (((unsigned)__popc((u7 & 63u) >> (9 - q)) ^ s21) & 1u) ? -Wk : Wk;
#pragma unroll
  for (int q = 9; q <= 20; ++q)
    acc[q] = (((y >> (21 - q)) ^ s21 ^ pu6) & 1u) ? -Wk : Wk;
  acc[21] = ((y ^ s21 ^ pu6) & 1u) ? -Wkb : Wkb;

  __syncthreads();
  float* red = (float*)lds4;                 // 4 waves * 23
  const int lane = t & 63, wv = t >> 6;
#pragma unroll
  for (int q = 0; q < 22; ++q) {
    float s = acc[q];
    for (int off = 32; off > 0; off >>= 1) s += __shfl_down(s, off, 64);
    if (lane == 0) red[wv * 23 + q] = s;
  }
  {
    float s = Tot;
    for (int off = 32; off > 0; off >>= 1) s += __shfl_down(s, off, 64);
    if (lane == 0) red[wv * 23 + 22] = s;
  }
  __syncthreads();
  if (t < 23) {
    float s = 0.f;
#pragma unroll
    for (int w = 0; w < 4; ++w) s += red[w * 23 + t];
    partials[t * 1024 + ((mid << 1) | a2)] = s;
  }
}

__global__ void k_final(const float* __restrict__ partials, float* __restrict__ out) {
  __shared__ double res[32];
  const int t = threadIdx.x;
  const int r = t >> 3, l8 = t & 7;
  if (r < 23) {
    double s = 0.0;
    const float* p = partials + r * 1024 + l8 * 128;
    for (int k = 0; k < 128; ++k) s += (double)p[k];
    for (int off = 4; off > 0; off >>= 1) s += __shfl_down(s, off, 8);
    if (l8 == 0) res[r] = s;
  }
  __syncthreads();
  if (t < 22) out[t] = (float)(res[t] / res[22]);  // normalization folded in
}

extern "C" void kernel_launch(void* const* d_in, const int* in_sizes, int n_in,
                              void* d_out, int out_size, void* d_ws, size_t ws_size,
                              hipStream_t stream) {
  const float* params = (const float*)d_in[0];   // [4][22][3]
  const float* sre = (const float*)d_in[1];      // [DIM]
  const float* sim = (const float*)d_in[2];      // [DIM]
  float* out = (float*)d_out;                    // [22]
  char* ws = (char*)d_ws;
  float* U = (float*)ws;                         // 88 * 8 floats
  float* partials = (float*)(ws + 4096);         // 23 * 1024 floats
  float2* buf0 = (float2*)(ws + 131072);         // 32 MB  (blocked: A out / B in)
  float2* buf1 = buf0 + DIM;                     // 32 MB  (T-permuted natural: B out / A in)

  k_gates<<<1, 128, 0, stream>>>(params, U);
  k_passA<<<1024, 256, 0, stream>>>(sre, sim, nullptr, buf0, U, 0, 1);
  k_passB<<<1024, 256, 0, stream>>>(buf0, buf1, U, 0);
  for (int l = 1; l < 3; ++l) {
    k_passA<<<1024, 256, 0, stream>>>(nullptr, nullptr, buf1, buf0, U, l, 0);
    k_passB<<<1024, 256, 0, stream>>>(buf0, buf1, U, l);
  }
  k_passA<<<1024, 256, 0, stream>>>(nullptr, nullptr, buf1, buf0, U, 3, 0);
  k_passB_ev<<<1024, 256, 0, stream>>>(buf0, U, partials, 3);
  k_final<<<1, 256, 0, stream>>>(partials, out);
}

// Round 7
// 189.099 us; speedup vs baseline: 1.1483x; 1.1483x over previous
//
#include <hip/hip_runtime.h>
#include <math.h>

#define NQ 22
#define DIM (1u << NQ)

typedef float v2f __attribute__((ext_vector_type(2)));

// ============================ 5-pass schedule ============================
// Circuit = A0 B0 T0 A1 B1 T1 A2 B2 T2 A3 B3 T3  (A = wires 21..10 = amp bits
// 0..11; B = wires 9..0 = amp bits 12..21; T = CNOT chain = invGray relabel,
// applied as t(x) = igray(x)). Single-qubit gates on disjoint wires commute,
// so regroup:
//   P1: B0            P2: A0,T0,A1      P3: B1,T1,B2      P4: A2,T2,A3
//   P5: B3 + expvals (T3 folded into Walsh signs)
// Labels: x -(T0)-> y -(T1)-> z -(T2)-> w.  In an A-block (bits 0..11 free,
// high fixed) the relabel restricts to a 12-bit bijection m_i = y_i =
// (x_i^..^x_11) ^ P, P = parity(high).  In a B-block freeing {0,1,11,12..21}
// the next layer's B-gates are single-bit gates on M_j = z_{11+j}, where
// M = suffix-xor of Y = (y11, yh0..yh9): z_{12+j} = M_{j+1} (j=0..9).
//
// Inter-pass layouts (float2 interleaved):
//   P1 out: natural x                      P2 in : contiguous float4
//   P2 out: L1(y) = y[2..10]<<13 | y[12..21]<<3 | y11<<2 | y1<<1 | y0
//   P3 in : contiguous 64KB chunk per block (fixed y[2..10])
//   P3 out: natural z                      P4 in : contiguous float4
//   P4 out: L3(w) = w[3..11]<<13 | w[12..21]<<3 | w[0..2]
//   P5 in : contiguous 64KB chunk per block (fixed w[3..11])

__device__ __forceinline__ unsigned igray(unsigned x) {
  x ^= x >> 1; x ^= x >> 2; x ^= x >> 4; x ^= x >> 8; x ^= x >> 16;
  return x;   // suffix-XOR: bit i = x_i ^ x_{i+1} ^ ...
}

// ---------------- fused gate matrices: U = RZ * RY * RX, fp64 -> fp32 ----------------
__global__ void k_gates(const float* __restrict__ params, float* __restrict__ U) {
  int t = blockIdx.x * blockDim.x + threadIdx.x;
  if (t >= 88) return;               // t = l*22 + q
  const float* p = params + t * 3;
  double hx = 0.5 * (double)p[0], hy = 0.5 * (double)p[1], hz = 0.5 * (double)p[2];
  double cx = cos(hx), sx = sin(hx);
  double cy = cos(hy), sy = sin(hy);
  double cz = cos(hz), sz = sin(hz);
  double m00r = cy * cx, m00i = sy * sx;
  double m01r = -sy * cx, m01i = -cy * sx;
  double m10r = sy * cx, m10i = -cy * sx;
  double m11r = cy * cx, m11i = -sy * sx;
  float* o = U + t * 8;
  o[0] = (float)(cz * m00r + sz * m00i); o[1] = (float)(cz * m00i - sz * m00r);
  o[2] = (float)(cz * m01r + sz * m01i); o[3] = (float)(cz * m01i - sz * m01r);
  o[4] = (float)(cz * m10r - sz * m10i); o[5] = (float)(cz * m10i + sz * m10r);
  o[6] = (float)(cz * m11r - sz * m11i); o[7] = (float)(cz * m11i + sz * m11r);
}

// ---------------- packed gate application ----------------
template <int NP>
__device__ __forceinline__ void apply_bit0(v2f RE[NP], v2f IM[NP], const float* __restrict__ u) {
  float u0 = u[0], u1 = u[1], u2 = u[2], u3 = u[3], u4 = u[4], u5 = u[5], u6 = u[6], u7 = u[7];
#pragma unroll
  for (int k = 0; k < NP; ++k) {
    float a0r = RE[k].x, a0i = IM[k].x, a1r = RE[k].y, a1i = IM[k].y;
    float n0r = u0 * a0r - u1 * a0i + u2 * a1r - u3 * a1i;
    float n0i = u0 * a0i + u1 * a0r + u2 * a1i + u3 * a1r;
    float n1r = u4 * a0r - u5 * a0i + u6 * a1r - u7 * a1i;
    float n1i = u4 * a0i + u5 * a0r + u6 * a1i + u7 * a1r;
    RE[k].x = n0r; IM[k].x = n0i; RE[k].y = n1r; IM[k].y = n1i;
  }
}

template <int NP, int PB>
__device__ __forceinline__ void apply_bitP(v2f RE[NP], v2f IM[NP], const float* __restrict__ u) {
  float u0 = u[0], u1 = u[1], u2 = u[2], u3 = u[3], u4 = u[4], u5 = u[5], u6 = u[6], u7 = u[7];
#pragma unroll
  for (int m = 0; m < NP / 2; ++m) {
    int k0 = ((m >> PB) << (PB + 1)) | (m & ((1 << PB) - 1));
    int k1 = k0 | (1 << PB);
    v2f a0r = RE[k0], a0i = IM[k0], a1r = RE[k1], a1i = IM[k1];
    v2f n0r = u0 * a0r - u1 * a0i + u2 * a1r - u3 * a1i;
    v2f n0i = u0 * a0i + u1 * a0r + u2 * a1i + u3 * a1r;
    v2f n1r = u4 * a0r - u5 * a0i + u6 * a1r - u7 * a1i;
    v2f n1i = u4 * a0i + u5 * a0r + u6 * a1i + u7 * a1r;
    RE[k0] = n0r; IM[k0] = n0i; RE[k1] = n1r; IM[k1] = n1i;
  }
}

__device__ __forceinline__ void apply4p(v2f RE[8], v2f IM[8], const float* __restrict__ U,
                                        int l, int wtop) {
  const float* base = U + ((l * 22 + wtop) << 3);
  apply_bit0<8>(RE, IM, base);
  apply_bitP<8, 0>(RE, IM, base - 8);
  apply_bitP<8, 1>(RE, IM, base - 16);
  apply_bitP<8, 2>(RE, IM, base - 24);
}

__device__ __forceinline__ void apply5p(v2f RE[16], v2f IM[16], const float* __restrict__ U,
                                        int l, int wtop) {
  const float* base = U + ((l * 22 + wtop) << 3);
  apply_bit0<16>(RE, IM, base);
  apply_bitP<16, 0>(RE, IM, base - 8);
  apply_bitP<16, 1>(RE, IM, base - 16);
  apply_bitP<16, 2>(RE, IM, base - 24);
  apply_bitP<16, 3>(RE, IM, base - 32);
}

// float2 LDS exchange for 16-amp state (sigma swizzle), 2 barriers.
template <typename WI, typename RI>
__device__ __forceinline__ void xchgP(float2* lds2, v2f RE[8], v2f IM[8], WI wi, RI ri) {
  __syncthreads();
#pragma unroll
  for (int d = 0; d < 16; ++d) {
    float2 a;
    if (d & 1) a = make_float2(RE[d >> 1].y, IM[d >> 1].y);
    else       a = make_float2(RE[d >> 1].x, IM[d >> 1].x);
    lds2[wi(d)] = a;
  }
  __syncthreads();
#pragma unroll
  for (int d = 0; d < 16; ++d) {
    float2 a = lds2[ri(d)];
    if (d & 1) { RE[d >> 1].y = a.x; IM[d >> 1].y = a.y; }
    else       { RE[d >> 1].x = a.x; IM[d >> 1].x = a.y; }
  }
}

__device__ __forceinline__ int pbf(unsigned e) {          // 13-bit B-pass swizzle
  return (int)(e ^ (((e >> 8) & 7u) << 3));
}

// ---------------- P1: B0 on x bits 12..21; in natural x, out natural x ----------------
__global__ __launch_bounds__(256, 2) void k_B0(const float* __restrict__ srcRe,
                                               const float* __restrict__ srcIm,
                                               float2* __restrict__ dst,
                                               const float* __restrict__ U) {
  __shared__ float2 lds2[8192];   // 64 KB
  const int t = threadIdx.x;
  const unsigned c = (unsigned)(t & 7), u = (unsigned)(t >> 3);
  const unsigned bid = blockIdx.x;
  const unsigned mid = (bid & 7u) * (gridDim.x >> 3) + (bid >> 3);   // x[3..11]
  const unsigned baselo = (mid << 3) | c;
  v2f RE[16], IM[16];
#pragma unroll
  for (int d = 0; d < 32; ++d) {             // slots d = x[17..21] (h bits 5..9)
    unsigned h = u | ((unsigned)d << 5);
    size_t x = ((size_t)h << 12) | baselo;
    float r = srcRe[x], i = srcIm[x];
    if (d & 1) { RE[d >> 1].y = r; IM[d >> 1].y = i; }
    else       { RE[d >> 1].x = r; IM[d >> 1].x = i; }
  }
  apply5p(RE, IM, U, 0, 4);                  // wires 4..0 = x bits 17..21
#pragma unroll
  for (int d = 0; d < 32; ++d) {
    unsigned e = ((u | ((unsigned)d << 5)) << 3) | c;
    float2 a;
    if (d & 1) a = make_float2(RE[d >> 1].y, IM[d >> 1].y);
    else       a = make_float2(RE[d >> 1].x, IM[d >> 1].x);
    lds2[pbf(e)] = a;
  }
  __syncthreads();
#pragma unroll
  for (int d = 0; d < 32; ++d) {             // now slots d = x[12..16]
    unsigned e = (((unsigned)d | (u << 5)) << 3) | c;
    float2 a = lds2[pbf(e)];
    if (d & 1) { RE[d >> 1].y = a.x; IM[d >> 1].y = a.y; }
    else       { RE[d >> 1].x = a.x; IM[d >> 1].x = a.y; }
  }
  apply5p(RE, IM, U, 0, 9);                  // wires 9..5 = x bits 12..16
#pragma unroll
  for (int d = 0; d < 32; ++d) {
    unsigned h = (unsigned)d | (u << 5);
    size_t x = ((size_t)h << 12) | baselo;
    float2 a;
    if (d & 1) a = make_float2(RE[d >> 1].y, IM[d >> 1].y);
    else       a = make_float2(RE[d >> 1].x, IM[d >> 1].x);
    dst[x] = a;
  }
}

// ---------------- P2/P4: fused A-pass  A_l, T_l, A_{l+1} ----------------
// Block: high 10 bits H fixed (grid 1024), local j = bits 0..11, 256 thr x 16.
// After layer l (3 phases over j bits 0..3/4..7/8..11), boundary exchange
// regathers by m = y-local: j(m) = m ^ (m>>1) ^ (P<<11), P = parity(H).
// MODE 0: store L1(y) (after P2).  MODE 1: store L3(w) (after P4).
template <int MODE>
__global__ __launch_bounds__(256, 4) void k_Afused(const float2* __restrict__ src,
                                                   float2* __restrict__ dst,
                                                   const float* __restrict__ U,
                                                   int l) {
  __shared__ float2 lds2[4096];   // 32 KB; phys = j ^ (j>>4)
  const int t = threadIdx.x;
  const unsigned bid = blockIdx.x;
  const unsigned H = (bid & 7u) * (gridDim.x >> 3) + (bid >> 3);
  const unsigned Pm = ((unsigned)(__popc(H) & 1)) << 11;
  v2f RE[8], IM[8];
  const float4* s4 = (const float4*)(src + (((size_t)H << 12) | ((size_t)t << 4)));
#pragma unroll
  for (int k = 0; k < 8; ++k) {              // j = t<<4 | d; lane = j bit 0
    float4 a = s4[k];
    RE[k].x = a.x; IM[k].x = a.y;
    RE[k].y = a.z; IM[k].y = a.w;
  }
  auto wA = [&](int d) { unsigned j = ((unsigned)t << 4) | (unsigned)d; return (int)(j ^ (j >> 4)); };
  auto rB = [&](int d) { unsigned j = (((unsigned)t >> 4) << 8) | ((unsigned)d << 4) | ((unsigned)t & 15); return (int)(j ^ (j >> 4)); };
  auto rC = [&](int d) { unsigned j = ((unsigned)d << 8) | (unsigned)t; return (int)(j ^ (j >> 4)); };
  auto rT = [&](int d) { unsigned m = ((unsigned)t << 4) | (unsigned)d;
                         unsigned j = (m ^ (m >> 1)) ^ Pm; return (int)(j ^ (j >> 4)); };

  apply4p(RE, IM, U, l, 21);        // layer l, bits 0..3  (wires 21..18)
  xchgP(lds2, RE, IM, wA, rB);
  apply4p(RE, IM, U, l, 17);        // bits 4..7
  xchgP(lds2, RE, IM, rB, rC);
  apply4p(RE, IM, U, l, 13);        // bits 8..11
  xchgP(lds2, RE, IM, rC, rT);      // T-relabel: slots now m = y-local, Arr-A shape
  apply4p(RE, IM, U, l + 1, 21);    // layer l+1, m bits 0..3
  xchgP(lds2, RE, IM, wA, rB);
  apply4p(RE, IM, U, l + 1, 17);    // m bits 4..7
  xchgP(lds2, RE, IM, rB, rC);
  apply4p(RE, IM, U, l + 1, 13);    // m bits 8..11; final: m = d<<8 | t
  const unsigned GH = igray(H);     // new-label high bits
  if (MODE == 0) {
    // L1: addr = m[2..10]<<13 | GH<<3 | m11<<2 | m1<<1 | m0
    float2* dp = dst + ((GH << 3) | ((unsigned)t & 3));
#pragma unroll
    for (int d = 0; d < 16; ++d) {
      float2 a;
      if (d & 1) a = make_float2(RE[d >> 1].y, IM[d >> 1].y);
      else       a = make_float2(RE[d >> 1].x, IM[d >> 1].x);
      unsigned addr = (((((unsigned)d & 7u) << 6) | ((unsigned)t >> 2)) << 13)
                    | ((((unsigned)d >> 3) & 1u) << 2);
      dp[addr] = a;
    }
  } else {
    // L3: addr = m[3..11]<<13 | GH<<3 | m[0..2]
    float2* dp = dst + ((GH << 3) | ((unsigned)t & 7));
#pragma unroll
    for (int d = 0; d < 16; ++d) {
      float2 a;
      if (d & 1) a = make_float2(RE[d >> 1].y, IM[d >> 1].y);
      else       a = make_float2(RE[d >> 1].x, IM[d >> 1].x);
      unsigned addr = ((((unsigned)d << 5) | ((unsigned)t >> 3)) << 13);
      dp[addr] = a;
    }
  }
}

// ---------------- P3: fused B-pass  B1, T1, B2 ----------------
// Block: fixed y[2..10] (grid 512); free {y0,y1,y11,yh=y[12..21]}; 256 thr x 32.
// t: low2 = (y0,y1); u6 = t>>2. Y = (y11, yh0..yh9); M_j = Y_j^..^Y_10;
// B2 gates are single-bit gates on M[1..10] (z_{11+j} = M_j). Store natural z:
//   z[12..21] = M[1..10]; zlow12 = CONSTK ^ M0*0xFFF ^ y1*3 ^ y0*1,
//   CONSTK bits: K_i = y_max(i,2)^..^y_10  (from igray(mid9)).
__device__ __forceinline__ int phi3(unsigned o) {
  return (int)(o ^ (((o >> 8) & 7u) << 3));
}

__global__ __launch_bounds__(256, 2) void k_Bfused(const float2* __restrict__ src,
                                                   float2* __restrict__ dst,
                                                   const float* __restrict__ U) {
  __shared__ float2 lds2[8192];   // 64 KB
  const int t = threadIdx.x;
  const unsigned low2 = (unsigned)(t & 3);
  const unsigned u6 = (unsigned)t >> 2;
  const unsigned uA = (u6 >> 1) & 31u, uB = u6 & 1u;   // 5-bit half, 1-bit half
  const unsigned bid = blockIdx.x;
  const unsigned mid = (bid & 7u) * (gridDim.x >> 3) + (bid >> 3);   // y[2..10]
  v2f RE[16], IM[16];
  // arr1: slots s = yh[5..9]; uA = yh[0..4], uB = y11. o = yh<<3|y11<<2|y1<<1|y0
  const float2* sp = src + (((size_t)mid << 13) | (uA << 3) | (uB << 2) | low2);
#pragma unroll
  for (int s = 0; s < 32; ++s) {
    float2 a = sp[(size_t)s << 8];
    if (s & 1) { RE[s >> 1].y = a.x; IM[s >> 1].y = a.y; }
    else       { RE[s >> 1].x = a.x; IM[s >> 1].x = a.y; }
  }
  apply5p(RE, IM, U, 1, 4);                  // B1: wires 4..0 = yh[5..9]
  // ex1 -> arr2: slots = yh[0..4]; uA = yh[5..9], uB = y11
#pragma unroll
  for (int s = 0; s < 32; ++s) {
    unsigned o = (((((unsigned)s << 5) | uA) << 3)) | (uB << 2) | low2;
    float2 a;
    if (s & 1) a = make_float2(RE[s >> 1].y, IM[s >> 1].y);
    else       a = make_float2(RE[s >> 1].x, IM[s >> 1].x);
    lds2[phi3(o)] = a;
  }
  __syncthreads();
#pragma unroll
  for (int s = 0; s < 32; ++s) {
    unsigned o = ((((uA << 5) | (unsigned)s) << 3)) | (uB << 2) | low2;
    float2 a = lds2[phi3(o)];
    if (s & 1) { RE[s >> 1].y = a.x; IM[s >> 1].y = a.y; }
    else       { RE[s >> 1].x = a.x; IM[s >> 1].x = a.y; }
  }
  __syncthreads();
  apply5p(RE, IM, U, 1, 9);                  // B1: wires 9..5 = yh[0..4]
  // ex2 -> arr3: slots = M[1..5]; uB = M0, uA = M[6..10]
#pragma unroll
  for (int s = 0; s < 32; ++s) {             // write from arr2
    unsigned o = ((((uA << 5) | (unsigned)s) << 3)) | (uB << 2) | low2;
    float2 a;
    if (s & 1) a = make_float2(RE[s >> 1].y, IM[s >> 1].y);
    else       a = make_float2(RE[s >> 1].x, IM[s >> 1].x);
    lds2[phi3(o)] = a;
  }
  __syncthreads();
#pragma unroll
  for (int s = 0; s < 32; ++s) {
    unsigned M = uB | ((unsigned)s << 1) | (uA << 6);
    unsigned Y = M ^ (M >> 1);               // Y_j = M_j ^ M_{j+1}
    unsigned o = ((Y >> 1) << 3) | ((Y & 1u) << 2) | low2;
    float2 a = lds2[phi3(o)];
    if (s & 1) { RE[s >> 1].y = a.x; IM[s >> 1].y = a.y; }
    else       { RE[s >> 1].x = a.x; IM[s >> 1].x = a.y; }
  }
  __syncthreads();
  apply5p(RE, IM, U, 2, 9);                  // B2: wires 9..5 = M[1..5] = z[12..16]
  // ex3 -> arr4: slots = M[6..10]; uB = M0, uA = M[1..5]
#pragma unroll
  for (int s = 0; s < 32; ++s) {             // write from arr3
    unsigned M = uB | ((unsigned)s << 1) | (uA << 6);
    unsigned Y = M ^ (M >> 1);
    unsigned o = ((Y >> 1) << 3) | ((Y & 1u) << 2) | low2;
    float2 a;
    if (s & 1) a = make_float2(RE[s >> 1].y, IM[s >> 1].y);
    else       a = make_float2(RE[s >> 1].x, IM[s >> 1].x);
    lds2[phi3(o)] = a;
  }
  __syncthreads();
#pragma unroll
  for (int s = 0; s < 32; ++s) {
    unsigned M = uB | (uA << 1) | ((unsigned)s << 6);
    unsigned Y = M ^ (M >> 1);
    unsigned o = ((Y >> 1) << 3) | ((Y & 1u) << 2) | low2;
    float2 a = lds2[phi3(o)];
    if (s & 1) { RE[s >> 1].y = a.x; IM[s >> 1].y = a.y; }
    else       { RE[s >> 1].x = a.x; IM[s >> 1].x = a.y; }
  }
  apply5p(RE, IM, U, 2, 4);                  // B2: wires 4..0 = M[6..10] = z[17..21]
  // store natural z
  const unsigned S9 = igray(mid);
  const unsigned CONSTK = (S9 << 2) | ((S9 & 1u) * 3u);
  const unsigned lowmix = (low2 & 1u) ^ (3u * ((low2 >> 1) & 1u));
  const unsigned zlow = CONSTK ^ (uB ? 0xFFFu : 0u) ^ lowmix;
#pragma unroll
  for (int s = 0; s < 32; ++s) {
    unsigned z = ((uA | ((unsigned)s << 5)) << 12) | zlow;   // z[12..21] = M[1..10]
    float2 a;
    if (s & 1) a = make_float2(RE[s >> 1].y, IM[s >> 1].y);
    else       a = make_float2(RE[s >> 1].x, IM[s >> 1].x);
    dst[z] = a;
  }
}

// ---------------- P5: B3 + expvals (final-T sign trick) ----------------
// Reads L3(w) blocked; amp bits: 0..2 = c, 3..11 = mid, 12..16 = u, 17..21 = d2.
__global__ __launch_bounds__(256, 2) void k_Bev(const float2* __restrict__ src,
                                                const float* __restrict__ U,
                                                float* __restrict__ partials) {
  __shared__ float2 lds2[8192];
  const int t = threadIdx.x;
  const unsigned c = (unsigned)(t & 7), u = (unsigned)(t >> 3);
  const unsigned bid = blockIdx.x;
  const unsigned mid = (bid & 7u) * (gridDim.x >> 3) + (bid >> 3);
  const float2* sp = src + (((size_t)mid << 13) | c);
  v2f RE[16], IM[16];
#pragma unroll
  for (int d = 0; d < 32; ++d) {
    unsigned h = u | ((unsigned)d << 5);
    float2 a = sp[(size_t)h << 3];
    if (d & 1) { RE[d >> 1].y = a.x; IM[d >> 1].y = a.y; }
    else       { RE[d >> 1].x = a.x; IM[d >> 1].x = a.y; }
  }
  apply5p(RE, IM, U, 3, 4);
#pragma unroll
  for (int d = 0; d < 32; ++d) {
    unsigned e = ((u | ((unsigned)d << 5)) << 3) | c;
    float2 a;
    if (d & 1) a = make_float2(RE[d >> 1].y, IM[d >> 1].y);
    else       a = make_float2(RE[d >> 1].x, IM[d >> 1].x);
    lds2[pbf(e)] = a;
  }
  __syncthreads();
#pragma unroll
  for (int d = 0; d < 32; ++d) {
    unsigned e = (((unsigned)d | (u << 5)) << 3) | c;
    float2 a = lds2[pbf(e)];
    if (d & 1) { RE[d >> 1].y = a.x; IM[d >> 1].y = a.y; }
    else       { RE[d >> 1].x = a.x; IM[d >> 1].x = a.y; }
  }
  apply5p(RE, IM, U, 3, 9);

  // Walsh fold over 5 slot bits (= w bits 12..16)
  v2f PS[16];
#pragma unroll
  for (int k = 0; k < 16; ++k) PS[k] = RE[k] * RE[k] + IM[k] * IM[k];
  v2f S4[8], B4[8];
#pragma unroll
  for (int k = 0; k < 8; ++k) { S4[k] = PS[k] + PS[k + 8]; B4[k] = PS[k] - PS[k + 8]; }
  float Tot = 0.f, W4 = 0.f;
#pragma unroll
  for (int k = 0; k < 8; ++k) { Tot += S4[k].x + S4[k].y; W4 += B4[k].x + B4[k].y; }
  v2f B3[4];
#pragma unroll
  for (int k = 0; k < 4; ++k) B3[k] = B4[k] - B4[k + 4];
  float W3 = (B3[0].x + B3[0].y) + (B3[1].x + B3[1].y) + (B3[2].x + B3[2].y) + (B3[3].x + B3[3].y);
  v2f B2[2];
  B2[0] = B3[0] - B3[2]; B2[1] = B3[1] - B3[3];
  float W2 = (B2[0].x + B2[0].y) + (B2[1].x + B2[1].y);
  v2f B1 = B2[0] - B2[1];
  float W1 = B1.x + B1.y;
  float W0 = B1.x - B1.y;

  unsigned lowfull = (mid << 3) | c;
  unsigned y = lowfull; y ^= y >> 1; y ^= y >> 2; y ^= y >> 4; y ^= y >> 8;
  unsigned pu = (unsigned)__popc(u) & 1u;
  float acc[22];
#pragma unroll
  for (int q = 0; q <= 4; ++q)
    acc[q] = ((unsigned)__popc(u >> (4 - q)) & 1u) ? -Tot : Tot;
  {
    float W[5] = {W0, W1, W2, W3, W4};
#pragma unroll
    for (int q = 5; q <= 9; ++q)
      acc[q] = pu ? -W[9 - q] : W[9 - q];
  }
#pragma unroll
  for (int q = 10; q <= 21; ++q)
    acc[q] = (((y >> (21 - q)) ^ pu) & 1u) ? -W0 : W0;

  __syncthreads();
  float* red = (float*)lds2;
  const int lane = t & 63, wv = t >> 6;
#pragma unroll
  for (int q = 0; q < 22; ++q) {
    float s = acc[q];
    for (int off = 32; off > 0; off >>= 1) s += __shfl_down(s, off, 64);
    if (lane == 0) red[wv * 23 + q] = s;
  }
  {
    float s = Tot;
    for (int off = 32; off > 0; off >>= 1) s += __shfl_down(s, off, 64);
    if (lane == 0) red[wv * 23 + 22] = s;
  }
  __syncthreads();
  if (t < 23) {
    float s = 0.f;
#pragma unroll
    for (int w = 0; w < 4; ++w) s += red[w * 23 + t];
    partials[t * 512 + mid] = s;
  }
}

__global__ void k_final(const float* __restrict__ partials, float* __restrict__ out) {
  __shared__ double res[32];
  const int t = threadIdx.x;
  const int r = t >> 3, l8 = t & 7;
  if (r < 23) {
    double s = 0.0;
    const float* p = partials + r * 512 + l8 * 64;
    for (int k = 0; k < 64; ++k) s += (double)p[k];
    for (int off = 4; off > 0; off >>= 1) s += __shfl_down(s, off, 8);
    if (l8 == 0) res[r] = s;
  }
  __syncthreads();
  if (t < 22) out[t] = (float)(res[t] / res[22]);
}

extern "C" void kernel_launch(void* const* d_in, const int* in_sizes, int n_in,
                              void* d_out, int out_size, void* d_ws, size_t ws_size,
                              hipStream_t stream) {
  const float* params = (const float*)d_in[0];   // [4][22][3]
  const float* sre = (const float*)d_in[1];      // [DIM]
  const float* sim = (const float*)d_in[2];      // [DIM]
  float* out = (float*)d_out;                    // [22]
  char* ws = (char*)d_ws;
  float* U = (float*)ws;                         // 88 * 8 floats
  float* partials = (float*)(ws + 4096);         // 23 * 512 floats
  float2* buf0 = (float2*)(ws + 131072);         // 32 MB
  float2* buf1 = buf0 + DIM;                     // 32 MB

  k_gates<<<1, 128, 0, stream>>>(params, U);
  k_B0<<<512, 256, 0, stream>>>(sre, sim, buf0, U);          // B0        (natural x)
  k_Afused<0><<<1024, 256, 0, stream>>>(buf0, buf1, U, 0);   // A0,T0,A1  (-> L1(y))
  k_Bfused<<<512, 256, 0, stream>>>(buf1, buf0, U);          // B1,T1,B2  (-> natural z)
  k_Afused<1><<<1024, 256, 0, stream>>>(buf0, buf1, U, 2);   // A2,T2,A3  (-> L3(w))
  k_Bev<<<512, 256, 0, stream>>>(buf1, U, partials);         // B3 + expvals
  k_final<<<1, 256, 0, stream>>>(partials, out);
}

// Round 8
// 186.604 us; speedup vs baseline: 1.1636x; 1.0134x over previous
//
#include <hip/hip_runtime.h>
#include <math.h>

#define NQ 22
#define DIM (1u << NQ)

typedef float v2f __attribute__((ext_vector_type(2)));

// ============================ 5-pass schedule ============================
// Circuit = A0 B0 T0 A1 B1 T1 A2 B2 T2 A3 B3 T3  (A = wires 21..10 = amp bits
// 0..11; B = wires 9..0 = amp bits 12..21; T = CNOT chain = invGray relabel,
// applied as t(x) = igray(x)). Single-qubit gates on disjoint wires commute,
// so regroup:
//   P1: B0            P2: A0,T0,A1      P3: B1,T1,B2      P4: A2,T2,A3
//   P5: B3 + expvals (T3 folded into Walsh signs)
// Labels: x -(T0)-> y -(T1)-> z -(T2)-> w.  In an A-block (bits 0..11 free,
// high fixed) the relabel restricts to a 12-bit bijection m_i = y_i =
// (x_i^..^x_11) ^ P, P = parity(high).  In a B-block freeing {0,1,11,12..21}
// the next layer's B-gates are single-bit gates on M_j = z_{11+j}, where
// M = suffix-xor of Y = (y11, yh0..yh9): z_{12+j} = M_{j+1} (j=0..9).
//
// Inter-pass layouts (float2 interleaved):
//   P1 out: natural x                      P2 in : contiguous float4
//   P2 out: L1(y) = y[2..10]<<13 | y[12..21]<<3 | y11<<2 | y1<<1 | y0
//   P3 in : contiguous 64KB chunk per block (fixed y[2..10])
//   P3 out: natural z                      P4 in : contiguous float4
//   P4 out: L3(w) = w[3..11]<<13 | w[12..21]<<3 | w[0..2]
//   P5 in : contiguous 64KB chunk per block (fixed w[3..11])
//
// R8: progressive load->compute interleave — phase-1 gate trees consume the
// load stream chunk-by-chunk (counted vmcnt) instead of draining it first.

__device__ __forceinline__ unsigned igray(unsigned x) {
  x ^= x >> 1; x ^= x >> 2; x ^= x >> 4; x ^= x >> 8; x ^= x >> 16;
  return x;   // suffix-XOR: bit i = x_i ^ x_{i+1} ^ ...
}

// ---------------- fused gate matrices: U = RZ * RY * RX, fp64 -> fp32 ----------------
__global__ void k_gates(const float* __restrict__ params, float* __restrict__ U) {
  int t = blockIdx.x * blockDim.x + threadIdx.x;
  if (t >= 88) return;               // t = l*22 + q
  const float* p = params + t * 3;
  double hx = 0.5 * (double)p[0], hy = 0.5 * (double)p[1], hz = 0.5 * (double)p[2];
  double cx = cos(hx), sx = sin(hx);
  double cy = cos(hy), sy = sin(hy);
  double cz = cos(hz), sz = sin(hz);
  double m00r = cy * cx, m00i = sy * sx;
  double m01r = -sy * cx, m01i = -cy * sx;
  double m10r = sy * cx, m10i = -cy * sx;
  double m11r = cy * cx, m11i = -sy * sx;
  float* o = U + t * 8;
  o[0] = (float)(cz * m00r + sz * m00i); o[1] = (float)(cz * m00i - sz * m00r);
  o[2] = (float)(cz * m01r + sz * m01i); o[3] = (float)(cz * m01i - sz * m01r);
  o[4] = (float)(cz * m10r - sz * m10i); o[5] = (float)(cz * m10i + sz * m10r);
  o[6] = (float)(cz * m11r - sz * m11i); o[7] = (float)(cz * m11i + sz * m11r);
}

// ---------------- packed gate application ----------------
template <int NP>
__device__ __forceinline__ void apply_bit0(v2f RE[NP], v2f IM[NP], const float* __restrict__ u) {
  float u0 = u[0], u1 = u[1], u2 = u[2], u3 = u[3], u4 = u[4], u5 = u[5], u6 = u[6], u7 = u[7];
#pragma unroll
  for (int k = 0; k < NP; ++k) {
    float a0r = RE[k].x, a0i = IM[k].x, a1r = RE[k].y, a1i = IM[k].y;
    float n0r = u0 * a0r - u1 * a0i + u2 * a1r - u3 * a1i;
    float n0i = u0 * a0i + u1 * a0r + u2 * a1i + u3 * a1r;
    float n1r = u4 * a0r - u5 * a0i + u6 * a1r - u7 * a1i;
    float n1i = u4 * a0i + u5 * a0r + u6 * a1i + u7 * a1r;
    RE[k].x = n0r; IM[k].x = n0i; RE[k].y = n1r; IM[k].y = n1i;
  }
}

template <int NP, int PB>
__device__ __forceinline__ void apply_bitP(v2f RE[NP], v2f IM[NP], const float* __restrict__ u) {
  float u0 = u[0], u1 = u[1], u2 = u[2], u3 = u[3], u4 = u[4], u5 = u[5], u6 = u[6], u7 = u[7];
#pragma unroll
  for (int m = 0; m < NP / 2; ++m) {
    int k0 = ((m >> PB) << (PB + 1)) | (m & ((1 << PB) - 1));
    int k1 = k0 | (1 << PB);
    v2f a0r = RE[k0], a0i = IM[k0], a1r = RE[k1], a1i = IM[k1];
    v2f n0r = u0 * a0r - u1 * a0i + u2 * a1r - u3 * a1i;
    v2f n0i = u0 * a0i + u1 * a0r + u2 * a1i + u3 * a1r;
    v2f n1r = u4 * a0r - u5 * a0i + u6 * a1r - u7 * a1i;
    v2f n1i = u4 * a0i + u5 * a0r + u6 * a1i + u7 * a1r;
    RE[k0] = n0r; IM[k0] = n0i; RE[k1] = n1r; IM[k1] = n1i;
  }
}

__device__ __forceinline__ void apply4p(v2f RE[8], v2f IM[8], const float* __restrict__ U,
                                        int l, int wtop) {
  const float* base = U + ((l * 22 + wtop) << 3);
  apply_bit0<8>(RE, IM, base);
  apply_bitP<8, 0>(RE, IM, base - 8);
  apply_bitP<8, 1>(RE, IM, base - 16);
  apply_bitP<8, 2>(RE, IM, base - 24);
}

__device__ __forceinline__ void apply5p(v2f RE[16], v2f IM[16], const float* __restrict__ U,
                                        int l, int wtop) {
  const float* base = U + ((l * 22 + wtop) << 3);
  apply_bit0<16>(RE, IM, base);
  apply_bitP<16, 0>(RE, IM, base - 8);
  apply_bitP<16, 1>(RE, IM, base - 16);
  apply_bitP<16, 2>(RE, IM, base - 24);
  apply_bitP<16, 3>(RE, IM, base - 32);
}

// Progressive phase-1 for 32-slot B kernels: raw float2 already loaded; per
// 8-slot chunk: unpack -> subtree (bit0,PB0,PB1); halves merge PB2; full PB3.
__device__ __forceinline__ void b_phase1_prog(v2f RE[16], v2f IM[16],
                                              const float2 raw[32],
                                              const float* __restrict__ base) {
#pragma unroll
  for (int q8 = 0; q8 < 4; ++q8) {
#pragma unroll
    for (int s = 0; s < 8; ++s) {
      float2 a = raw[8 * q8 + s];
      int p = 4 * q8 + (s >> 1);
      if (s & 1) { RE[p].y = a.x; IM[p].y = a.y; }
      else       { RE[p].x = a.x; IM[p].x = a.y; }
    }
    apply_bit0<4>(&RE[4 * q8], &IM[4 * q8], base);
    apply_bitP<4, 0>(&RE[4 * q8], &IM[4 * q8], base - 8);
    apply_bitP<4, 1>(&RE[4 * q8], &IM[4 * q8], base - 16);
    if (q8 == 1) apply_bitP<8, 2>(&RE[0], &IM[0], base - 24);
    if (q8 == 3) apply_bitP<8, 2>(&RE[8], &IM[8], base - 24);
  }
  apply_bitP<16, 3>(RE, IM, base - 32);
}

// float2 LDS exchange for 16-amp state (sigma swizzle), 2 barriers.
template <typename WI, typename RI>
__device__ __forceinline__ void xchgP(float2* lds2, v2f RE[8], v2f IM[8], WI wi, RI ri) {
  __syncthreads();
#pragma unroll
  for (int d = 0; d < 16; ++d) {
    float2 a;
    if (d & 1) a = make_float2(RE[d >> 1].y, IM[d >> 1].y);
    else       a = make_float2(RE[d >> 1].x, IM[d >> 1].x);
    lds2[wi(d)] = a;
  }
  __syncthreads();
#pragma unroll
  for (int d = 0; d < 16; ++d) {
    float2 a = lds2[ri(d)];
    if (d & 1) { RE[d >> 1].y = a.x; IM[d >> 1].y = a.y; }
    else       { RE[d >> 1].x = a.x; IM[d >> 1].x = a.y; }
  }
}

__device__ __forceinline__ int pbf(unsigned e) {          // 13-bit B-pass swizzle
  return (int)(e ^ (((e >> 8) & 7u) << 3));
}

// ---------------- P1: B0 on x bits 12..21; in natural x, out natural x ----------------
__global__ __launch_bounds__(256, 2) void k_B0(const float* __restrict__ srcRe,
                                               const float* __restrict__ srcIm,
                                               float2* __restrict__ dst,
                                               const float* __restrict__ U) {
  __shared__ float2 lds2[8192];   // 64 KB
  const int t = threadIdx.x;
  const unsigned c = (unsigned)(t & 7), u = (unsigned)(t >> 3);
  const unsigned bid = blockIdx.x;
  const unsigned mid = (bid & 7u) * (gridDim.x >> 3) + (bid >> 3);   // x[3..11]
  const unsigned baselo = (mid << 3) | c;
  v2f RE[16], IM[16];
  float2 raw[32];
#pragma unroll
  for (int s = 0; s < 32; ++s) {             // slots s = x[17..21] (h bits 5..9)
    unsigned h = u | ((unsigned)s << 5);
    size_t x = ((size_t)h << 12) | baselo;
    raw[s].x = srcRe[x];
    raw[s].y = srcIm[x];
  }
  b_phase1_prog(RE, IM, raw, U + ((0 * 22 + 4) << 3));   // wires 4..0 = x bits 17..21
#pragma unroll
  for (int d = 0; d < 32; ++d) {
    unsigned e = ((u | ((unsigned)d << 5)) << 3) | c;
    float2 a;
    if (d & 1) a = make_float2(RE[d >> 1].y, IM[d >> 1].y);
    else       a = make_float2(RE[d >> 1].x, IM[d >> 1].x);
    lds2[pbf(e)] = a;
  }
  __syncthreads();
#pragma unroll
  for (int d = 0; d < 32; ++d) {             // now slots d = x[12..16]
    unsigned e = (((unsigned)d | (u << 5)) << 3) | c;
    float2 a = lds2[pbf(e)];
    if (d & 1) { RE[d >> 1].y = a.x; IM[d >> 1].y = a.y; }
    else       { RE[d >> 1].x = a.x; IM[d >> 1].x = a.y; }
  }
  apply5p(RE, IM, U, 0, 9);                  // wires 9..5 = x bits 12..16
#pragma unroll
  for (int d = 0; d < 32; ++d) {
    unsigned h = (unsigned)d | (u << 5);
    size_t x = ((size_t)h << 12) | baselo;
    float2 a;
    if (d & 1) a = make_float2(RE[d >> 1].y, IM[d >> 1].y);
    else       a = make_float2(RE[d >> 1].x, IM[d >> 1].x);
    dst[x] = a;
  }
}

// ---------------- P2/P4: fused A-pass  A_l, T_l, A_{l+1} ----------------
// Block: high 10 bits H fixed (grid 1024), local j = bits 0..11, 256 thr x 16.
// After layer l (3 phases over j bits 0..3/4..7/8..11), boundary exchange
// regathers by m = y-local: j(m) = m ^ (m>>1) ^ (P<<11), P = parity(H).
// MODE 0: store L1(y) (after P2).  MODE 1: store L3(w) (after P4).
template <int MODE>
__global__ __launch_bounds__(256, 4) void k_Afused(const float2* __restrict__ src,
                                                   float2* __restrict__ dst,
                                                   const float* __restrict__ U,
                                                   int l) {
  __shared__ float2 lds2[4096];   // 32 KB; phys = j ^ (j>>4)
  const int t = threadIdx.x;
  const unsigned bid = blockIdx.x;
  const unsigned H = (bid & 7u) * (gridDim.x >> 3) + (bid >> 3);
  const unsigned Pm = ((unsigned)(__popc(H) & 1)) << 11;
  v2f RE[8], IM[8];
  const float4* s4 = (const float4*)(src + (((size_t)H << 12) | ((size_t)t << 4)));
  float4 raw[8];
#pragma unroll
  for (int k = 0; k < 8; ++k) raw[k] = s4[k];
  {  // progressive phase 1: bits 0..3 (wires 21..18 of layer l)
    const float* base = U + ((l * 22 + 21) << 3);
#pragma unroll
    for (int h4 = 0; h4 < 2; ++h4) {
#pragma unroll
      for (int k = 0; k < 4; ++k) {
        float4 a = raw[4 * h4 + k];
        RE[4 * h4 + k].x = a.x; IM[4 * h4 + k].x = a.y;
        RE[4 * h4 + k].y = a.z; IM[4 * h4 + k].y = a.w;
      }
      apply_bit0<4>(&RE[4 * h4], &IM[4 * h4], base);
      apply_bitP<4, 0>(&RE[4 * h4], &IM[4 * h4], base - 8);
      apply_bitP<4, 1>(&RE[4 * h4], &IM[4 * h4], base - 16);
    }
    apply_bitP<8, 2>(RE, IM, base - 24);
  }
  auto wA = [&](int d) { unsigned j = ((unsigned)t << 4) | (unsigned)d; return (int)(j ^ (j >> 4)); };
  auto rB = [&](int d) { unsigned j = (((unsigned)t >> 4) << 8) | ((unsigned)d << 4) | ((unsigned)t & 15); return (int)(j ^ (j >> 4)); };
  auto rC = [&](int d) { unsigned j = ((unsigned)d << 8) | (unsigned)t; return (int)(j ^ (j >> 4)); };
  auto rT = [&](int d) { unsigned m = ((unsigned)t << 4) | (unsigned)d;
                         unsigned j = (m ^ (m >> 1)) ^ Pm; return (int)(j ^ (j >> 4)); };

  xchgP(lds2, RE, IM, wA, rB);
  apply4p(RE, IM, U, l, 17);        // bits 4..7
  xchgP(lds2, RE, IM, rB, rC);
  apply4p(RE, IM, U, l, 13);        // bits 8..11
  xchgP(lds2, RE, IM, rC, rT);      // T-relabel: slots now m = y-local, Arr-A shape
  apply4p(RE, IM, U, l + 1, 21);    // layer l+1, m bits 0..3
  xchgP(lds2, RE, IM, wA, rB);
  apply4p(RE, IM, U, l + 1, 17);    // m bits 4..7
  xchgP(lds2, RE, IM, rB, rC);
  apply4p(RE, IM, U, l + 1, 13);    // m bits 8..11; final: m = d<<8 | t
  const unsigned GH = igray(H);     // new-label high bits
  if (MODE == 0) {
    // L1: addr = m[2..10]<<13 | GH<<3 | m11<<2 | m1<<1 | m0
    float2* dp = dst + ((GH << 3) | ((unsigned)t & 3));
#pragma unroll
    for (int d = 0; d < 16; ++d) {
      float2 a;
      if (d & 1) a = make_float2(RE[d >> 1].y, IM[d >> 1].y);
      else       a = make_float2(RE[d >> 1].x, IM[d >> 1].x);
      unsigned addr = (((((unsigned)d & 7u) << 6) | ((unsigned)t >> 2)) << 13)
                    | ((((unsigned)d >> 3) & 1u) << 2);
      dp[addr] = a;
    }
  } else {
    // L3: addr = m[3..11]<<13 | GH<<3 | m[0..2]
    float2* dp = dst + ((GH << 3) | ((unsigned)t & 7));
#pragma unroll
    for (int d = 0; d < 16; ++d) {
      float2 a;
      if (d & 1) a = make_float2(RE[d >> 1].y, IM[d >> 1].y);
      else       a = make_float2(RE[d >> 1].x, IM[d >> 1].x);
      unsigned addr = ((((unsigned)d << 5) | ((unsigned)t >> 3)) << 13);
      dp[addr] = a;
    }
  }
}

// ---------------- P3: fused B-pass  B1, T1, B2 ----------------
// Block: fixed y[2..10] (grid 512); free {y0,y1,y11,yh=y[12..21]}; 256 thr x 32.
// t: low2 = (y0,y1); u6 = t>>2. Y = (y11, yh0..yh9); M_j = Y_j^..^Y_10;
// B2 gates are single-bit gates on M[1..10] (z_{11+j} = M_j). Store natural z:
//   z[12..21] = M[1..10]; zlow12 = CONSTK ^ M0*0xFFF ^ y1*3 ^ y0*1,
//   CONSTK bits: K_i = y_max(i,2)^..^y_10  (from igray(mid9)).
__device__ __forceinline__ int phi3(unsigned o) {
  return (int)(o ^ (((o >> 8) & 7u) << 3));
}

__global__ __launch_bounds__(256, 2) void k_Bfused(const float2* __restrict__ src,
                                                   float2* __restrict__ dst,
                                                   const float* __restrict__ U) {
  __shared__ float2 lds2[8192];   // 64 KB
  const int t = threadIdx.x;
  const unsigned low2 = (unsigned)(t & 3);
  const unsigned u6 = (unsigned)t >> 2;
  const unsigned uA = (u6 >> 1) & 31u, uB = u6 & 1u;   // 5-bit half, 1-bit half
  const unsigned bid = blockIdx.x;
  const unsigned mid = (bid & 7u) * (gridDim.x >> 3) + (bid >> 3);   // y[2..10]
  v2f RE[16], IM[16];
  // arr1: slots s = yh[5..9]; uA = yh[0..4], uB = y11. o = yh<<3|y11<<2|y1<<1|y0
  const float2* sp = src + (((size_t)mid << 13) | (uA << 3) | (uB << 2) | low2);
  float2 raw[32];
#pragma unroll
  for (int s = 0; s < 32; ++s) raw[s] = sp[(size_t)s << 8];
  b_phase1_prog(RE, IM, raw, U + ((1 * 22 + 4) << 3));   // B1: wires 4..0 = yh[5..9]
  // ex1 -> arr2: slots = yh[0..4]; uA = yh[5..9], uB = y11
#pragma unroll
  for (int s = 0; s < 32; ++s) {
    unsigned o = (((((unsigned)s << 5) | uA) << 3)) | (uB << 2) | low2;
    float2 a;
    if (s & 1) a = make_float2(RE[s >> 1].y, IM[s >> 1].y);
    else       a = make_float2(RE[s >> 1].x, IM[s >> 1].x);
    lds2[phi3(o)] = a;
  }
  __syncthreads();
#pragma unroll
  for (int s = 0; s < 32; ++s) {
    unsigned o = ((((uA << 5) | (unsigned)s) << 3)) | (uB << 2) | low2;
    float2 a = lds2[phi3(o)];
    if (s & 1) { RE[s >> 1].y = a.x; IM[s >> 1].y = a.y; }
    else       { RE[s >> 1].x = a.x; IM[s >> 1].x = a.y; }
  }
  __syncthreads();
  apply5p(RE, IM, U, 1, 9);                  // B1: wires 9..5 = yh[0..4]
  // ex2 -> arr3: slots = M[1..5]; uB = M0, uA = M[6..10]
#pragma unroll
  for (int s = 0; s < 32; ++s) {             // write from arr2
    unsigned o = ((((uA << 5) | (unsigned)s) << 3)) | (uB << 2) | low2;
    float2 a;
    if (s & 1) a = make_float2(RE[s >> 1].y, IM[s >> 1].y);
    else       a = make_float2(RE[s >> 1].x, IM[s >> 1].x);
    lds2[phi3(o)] = a;
  }
  __syncthreads();
#pragma unroll
  for (int s = 0; s < 32; ++s) {
    unsigned M = uB | ((unsigned)s << 1) | (uA << 6);
    unsigned Y = M ^ (M >> 1);               // Y_j = M_j ^ M_{j+1}
    unsigned o = ((Y >> 1) << 3) | ((Y & 1u) << 2) | low2;
    float2 a = lds2[phi3(o)];
    if (s & 1) { RE[s >> 1].y = a.x; IM[s >> 1].y = a.y; }
    else       { RE[s >> 1].x = a.x; IM[s >> 1].x = a.y; }
  }
  __syncthreads();
  apply5p(RE, IM, U, 2, 9);                  // B2: wires 9..5 = M[1..5] = z[12..16]
  // ex3 -> arr4: slots = M[6..10]; uB = M0, uA = M[1..5]
#pragma unroll
  for (int s = 0; s < 32; ++s) {             // write from arr3
    unsigned M = uB | ((unsigned)s << 1) | (uA << 6);
    unsigned Y = M ^ (M >> 1);
    unsigned o = ((Y >> 1) << 3) | ((Y & 1u) << 2) | low2;
    float2 a;
    if (s & 1) a = make_float2(RE[s >> 1].y, IM[s >> 1].y);
    else       a = make_float2(RE[s >> 1].x, IM[s >> 1].x);
    lds2[phi3(o)] = a;
  }
  __syncthreads();
#pragma unroll
  for (int s = 0; s < 32; ++s) {
    unsigned M = uB | (uA << 1) | ((unsigned)s << 6);
    unsigned Y = M ^ (M >> 1);
    unsigned o = ((Y >> 1) << 3) | ((Y & 1u) << 2) | low2;
    float2 a = lds2[phi3(o)];
    if (s & 1) { RE[s >> 1].y = a.x; IM[s >> 1].y = a.y; }
    else       { RE[s >> 1].x = a.x; IM[s >> 1].x = a.y; }
  }
  apply5p(RE, IM, U, 2, 4);                  // B2: wires 4..0 = M[6..10] = z[17..21]
  // store natural z
  const unsigned S9 = igray(mid);
  const unsigned CONSTK = (S9 << 2) | ((S9 & 1u) * 3u);
  const unsigned lowmix = (low2 & 1u) ^ (3u * ((low2 >> 1) & 1u));
  const unsigned zlow = CONSTK ^ (uB ? 0xFFFu : 0u) ^ lowmix;
#pragma unroll
  for (int s = 0; s < 32; ++s) {
    unsigned z = ((uA | ((unsigned)s << 5)) << 12) | zlow;   // z[12..21] = M[1..10]
    float2 a;
    if (s & 1) a = make_float2(RE[s >> 1].y, IM[s >> 1].y);
    else       a = make_float2(RE[s >> 1].x, IM[s >> 1].x);
    dst[z] = a;
  }
}

// ---------------- P5: B3 + expvals (final-T sign trick) ----------------
// Reads L3(w) blocked; amp bits: 0..2 = c, 3..11 = mid, 12..16 = u, 17..21 = d2.
__global__ __launch_bounds__(256, 2) void k_Bev(const float2* __restrict__ src,
                                                const float* __restrict__ U,
                                                float* __restrict__ partials) {
  __shared__ float2 lds2[8192];
  const int t = threadIdx.x;
  const unsigned c = (unsigned)(t & 7), u = (unsigned)(t >> 3);
  const unsigned bid = blockIdx.x;
  const unsigned mid = (bid & 7u) * (gridDim.x >> 3) + (bid >> 3);
  const float2* sp = src + (((size_t)mid << 13) | c);
  v2f RE[16], IM[16];
  float2 raw[32];
#pragma unroll
  for (int s = 0; s < 32; ++s) raw[s] = sp[(size_t)(u | ((unsigned)s << 5)) << 3];
  b_phase1_prog(RE, IM, raw, U + ((3 * 22 + 4) << 3));
#pragma unroll
  for (int d = 0; d < 32; ++d) {
    unsigned e = ((u | ((unsigned)d << 5)) << 3) | c;
    float2 a;
    if (d & 1) a = make_float2(RE[d >> 1].y, IM[d >> 1].y);
    else       a = make_float2(RE[d >> 1].x, IM[d >> 1].x);
    lds2[pbf(e)] = a;
  }
  __syncthreads();
#pragma unroll
  for (int d = 0; d < 32; ++d) {
    unsigned e = (((unsigned)d | (u << 5)) << 3) | c;
    float2 a = lds2[pbf(e)];
    if (d & 1) { RE[d >> 1].y = a.x; IM[d >> 1].y = a.y; }
    else       { RE[d >> 1].x = a.x; IM[d >> 1].x = a.y; }
  }
  apply5p(RE, IM, U, 3, 9);

  // Walsh fold over 5 slot bits (= w bits 12..16)
  v2f PS[16];
#pragma unroll
  for (int k = 0; k < 16; ++k) PS[k] = RE[k] * RE[k] + IM[k] * IM[k];
  v2f S4[8], B4[8];
#pragma unroll
  for (int k = 0; k < 8; ++k) { S4[k] = PS[k] + PS[k + 8]; B4[k] = PS[k] - PS[k + 8]; }
  float Tot = 0.f, W4 = 0.f;
#pragma unroll
  for (int k = 0; k < 8; ++k) { Tot += S4[k].x + S4[k].y; W4 += B4[k].x + B4[k].y; }
  v2f B3[4];
#pragma unroll
  for (int k = 0; k < 4; ++k) B3[k] = B4[k] - B4[k + 4];
  float W3 = (B3[0].x + B3[0].y) + (B3[1].x + B3[1].y) + (B3[2].x + B3[2].y) + (B3[3].x + B3[3].y);
  v2f B2[2];
  B2[0] = B3[0] - B3[2]; B2[1] = B3[1] - B3[3];
  float W2 = (B2[0].x + B2[0].y) + (B2[1].x + B2[1].y);
  v2f B1 = B2[0] - B2[1];
  float W1 = B1.x + B1.y;
  float W0 = B1.x - B1.y;

  unsigned lowfull = (mid << 3) | c;
  unsigned y = lowfull; y ^= y >> 1; y ^= y >> 2; y ^= y >> 4; y ^= y >> 8;
  unsigned pu = (unsigned)__popc(u) & 1u;
  float acc[22];
#pragma unroll
  for (int q = 0; q <= 4; ++q)
    acc[q] = ((unsigned)__popc(u >> (4 - q)) & 1u) ? -Tot : Tot;
  {
    float W[5] = {W0, W1, W2, W3, W4};
#pragma unroll
    for (int q = 5; q <= 9; ++q)
      acc[q] = pu ? -W[9 - q] : W[9 - q];
  }
#pragma unroll
  for (int q = 10; q <= 21; ++q)
    acc[q] = (((y >> (21 - q)) ^ pu) & 1u) ? -W0 : W0;

  __syncthreads();
  float* red = (float*)lds2;
  const int lane = t & 63, wv = t >> 6;
#pragma unroll
  for (int q = 0; q < 22; ++q) {
    float s = acc[q];
    for (int off = 32; off > 0; off >>= 1) s += __shfl_down(s, off, 64);
    if (lane == 0) red[wv * 23 + q] = s;
  }
  {
    float s = Tot;
    for (int off = 32; off > 0; off >>= 1) s += __shfl_down(s, off, 64);
    if (lane == 0) red[wv * 23 + 22] = s;
  }
  __syncthreads();
  if (t < 23) {
    float s = 0.f;
#pragma unroll
    for (int w = 0; w < 4; ++w) s += red[w * 23 + t];
    partials[t * 512 + mid] = s;
  }
}

__global__ void k_final(const float* __restrict__ partials, float* __restrict__ out) {
  __shared__ double res[32];
  const int t = threadIdx.x;
  const int r = t >> 3, l8 = t & 7;
  if (r < 23) {
    double s = 0.0;
    const float* p = partials + r * 512 + l8 * 64;
    for (int k = 0; k < 64; ++k) s += (double)p[k];
    for (int off = 4; off > 0; off >>= 1) s += __shfl_down(s, off, 8);
    if (l8 == 0) res[r] = s;
  }
  __syncthreads();
  if (t < 22) out[t] = (float)(res[t] / res[22]);
}

extern "C" void kernel_launch(void* const* d_in, const int* in_sizes, int n_in,
                              void* d_out, int out_size, void* d_ws, size_t ws_size,
                              hipStream_t stream) {
  const float* params = (const float*)d_in[0];   // [4][22][3]
  const float* sre = (const float*)d_in[1];      // [DIM]
  const float* sim = (const float*)d_in[2];      // [DIM]
  float* out = (float*)d_out;                    // [22]
  char* ws = (char*)d_ws;
  float* U = (float*)ws;                         // 88 * 8 floats
  float* partials = (float*)(ws + 4096);         // 23 * 512 floats
  float2* buf0 = (float2*)(ws + 131072);         // 32 MB
  float2* buf1 = buf0 + DIM;                     // 32 MB

  k_gates<<<1, 128, 0, stream>>>(params, U);
  k_B0<<<512, 256, 0, stream>>>(sre, sim, buf0, U);          // B0        (natural x)
  k_Afused<0><<<1024, 256, 0, stream>>>(buf0, buf1, U, 0);   // A0,T0,A1  (-> L1(y))
  k_Bfused<<<512, 256, 0, stream>>>(buf1, buf0, U);          // B1,T1,B2  (-> natural z)
  k_Afused<1><<<1024, 256, 0, stream>>>(buf0, buf1, U, 2);   // A2,T2,A3  (-> L3(w))
  k_Bev<<<512, 256, 0, stream>>>(buf1, U, partials);         // B3 + expvals
  k_final<<<1, 256, 0, stream>>>(partials, out);
}